// Round 3
// baseline (144.699 us; speedup 1.0000x reference)
//
#include <hip/hip_runtime.h>
#include <hip/hip_bf16.h>
#include <math.h>

// Problem constants: B=256, V=2048, PD=1024, MD=512, H=512
typedef __attribute__((ext_vector_type(8))) short short8;
typedef __attribute__((ext_vector_type(4))) float float4v;
typedef __attribute__((ext_vector_type(2))) float float2v;

// SSA-safe half extraction (NO unions -- unions block SROA and spill).
__device__ __forceinline__ float2v lo2(float4v v) {
    return __builtin_shufflevector(v, v, 0, 1);
}
__device__ __forceinline__ float2v hi2(float4v v) {
    return __builtin_shufflevector(v, v, 2, 3);
}

__device__ __forceinline__ int2 cvt2bf16x4(float4v v) {
    union { __hip_bfloat162 h2; int i; } u0, u1;
    u0.h2 = __float22bfloat162_rn(make_float2(v.x, v.y));  // v_cvt_pk_bf16_f32
    u1.h2 = __float22bfloat162_rn(make_float2(v.z, v.w));
    return make_int2(u0.i, u1.i);
}

// Fused dual GEMM + exp epilogue (plain [h][x] layout, contiguous stores).
//  z==0: EA[h][b] = exp(2*(patient@W1p^T + b1))   M=256,  K=1024
//  z==1: EM[h][v] = exp(2*(atc4@W1m^T))           M=2048, K=512
// Also zeroes the pair-kernel's tile counters (kernel-boundary visibility).
__global__ __launch_bounds__(256) void gemm_exp(
    const float* __restrict__ patient, const float* __restrict__ atc4,
    const float* __restrict__ W1, const float* __restrict__ b1,
    float* __restrict__ EA, float* __restrict__ EM, int* __restrict__ ctr)
{
    if (blockIdx.z == 0 && blockIdx.x == 0 && blockIdx.y == 0 && threadIdx.x < 64)
        ctr[threadIdx.x] = 0;

    const float* A; const float* W; const float* bias; float* T;
    int lda, K, M;
    if (blockIdx.z == 0) {
        if (blockIdx.x >= 4) return;           // 4x8 tiles cover 256x512
        A = patient; lda = 1024; K = 1024; M = 256; bias = b1; T = EA; W = W1;
    } else {
        A = atc4;    lda = 512;  K = 512;  M = 2048; bias = nullptr; T = EM; W = W1 + 1024;
    }
    const int ldw = 1536;

    __shared__ short As[64][72];
    __shared__ short Bs[64][72];
    const int t = threadIdx.x;
    const int m0 = blockIdx.x * 64;
    const int n0 = blockIdx.y * 64;
    const int wave = t >> 6;
    const int lane = t & 63;
    const int wm = (wave & 1) * 32;
    const int wn = (wave >> 1) * 32;
    const int lrow = lane & 15;
    const int quad = lane >> 4;

    float4v acc[2][2];
    #pragma unroll
    for (int i = 0; i < 2; i++)
        #pragma unroll
        for (int j = 0; j < 2; j++)
            acc[i][j] = (float4v){0.f, 0.f, 0.f, 0.f};

    const int sr = t >> 2;        // staging row 0..63
    const int sc = (t & 3) * 16;  // staging col 0,16,32,48

    // preload k-tile 0 into registers
    float4v av[4], wv[4];
    {
        const float* ap = A + (size_t)(m0 + sr) * lda + sc;
        const float* wp = W + (size_t)(n0 + sr) * ldw + sc;
        #pragma unroll
        for (int ii = 0; ii < 4; ii++) {
            av[ii] = *(const float4v*)(ap + ii * 4);
            wv[ii] = *(const float4v*)(wp + ii * 4);
        }
    }

    for (int k0 = 0; k0 < K; k0 += 64) {
        #pragma unroll
        for (int ii = 0; ii < 4; ii++) {
            *(int2*)&As[sr][sc + ii * 4] = cvt2bf16x4(av[ii]);
            *(int2*)&Bs[sr][sc + ii * 4] = cvt2bf16x4(wv[ii]);
        }
        __syncthreads();
        if (k0 + 64 < K) {   // prefetch next k-tile; latency hides under MFMA
            const float* ap = A + (size_t)(m0 + sr) * lda + (k0 + 64 + sc);
            const float* wp = W + (size_t)(n0 + sr) * ldw + (k0 + 64 + sc);
            #pragma unroll
            for (int ii = 0; ii < 4; ii++) {
                av[ii] = *(const float4v*)(ap + ii * 4);
                wv[ii] = *(const float4v*)(wp + ii * 4);
            }
        }
        #pragma unroll
        for (int kk = 0; kk < 64; kk += 32) {
            short8 af[2], bfr[2];
            #pragma unroll
            for (int i = 0; i < 2; i++)
                af[i] = *(const short8*)&As[wm + i * 16 + lrow][kk + quad * 8];
            #pragma unroll
            for (int j = 0; j < 2; j++)
                bfr[j] = *(const short8*)&Bs[wn + j * 16 + lrow][kk + quad * 8];
            #pragma unroll
            for (int i = 0; i < 2; i++)
                #pragma unroll
                for (int j = 0; j < 2; j++)
                    acc[i][j] = __builtin_amdgcn_mfma_f32_16x16x32_bf16(
                        af[i], bfr[j], acc[i][j], 0, 0, 0);
        }
        __syncthreads();
    }

    // D layout (verified m89/m91): col(n)=lane&15, row(m)=quad*4+reg
    #pragma unroll
    for (int i = 0; i < 2; i++) {
        #pragma unroll
        for (int j = 0; j < 2; j++) {
            const int n  = n0 + wn + j * 16 + lrow;
            const int mb = m0 + wm + i * 16 + quad * 4;
            const float bn = bias ? bias[n] : 0.0f;
            float4v ev;
            #pragma unroll
            for (int r = 0; r < 4; r++)
                ev[r] = __expf(2.0f * (acc[i][j][r] + bn));
            *(float4v*)&T[(size_t)n * M + mb] = ev;
        }
    }
}

// 4-h rational block: acc += sum_{k=0..3} c_k / d_k, d_k = 1 + em_k*a_k.
//   (n01*e23 + n23*e01)/(e01*e23); all d >= 1 so no cancellation.
__device__ __forceinline__ void rat4(
    float2v em0, float2v em1, float2v em2, float2v em3,
    float2v a0, float2v a1, float2v a2, float2v a3,
    float2v c0, float2v c1, float2v c2, float2v c3,
    float2v& acc)
{
    const float2v one2 = {1.f, 1.f};
    float2v d0 = __builtin_elementwise_fma(em0, a0, one2);
    float2v d1 = __builtin_elementwise_fma(em1, a1, one2);
    float2v d2 = __builtin_elementwise_fma(em2, a2, one2);
    float2v d3 = __builtin_elementwise_fma(em3, a3, one2);
    float2v e01 = d0 * d1;
    float2v e23 = d2 * d3;
    float2v n01 = __builtin_elementwise_fma(d1, c0, d0 * c1);
    float2v n23 = __builtin_elementwise_fma(d3, c2, d2 * c3);
    float2v num = __builtin_elementwise_fma(n01, e23, n23 * e01);
    float2v den = e01 * e23;
    float2v r = { __builtin_amdgcn_rcpf(den.x), __builtin_amdgcn_rcpf(den.y) };
    acc = __builtin_elementwise_fma(num, r, acc);
}

// partial[z][b][v] = sum_{h in 128-chunk z} [ w2[h] + c_h / d_h ]
// Round 3: (a) double-buffered LDS -- one barrier per stage, ds_writes of the
// next stage overlap compute of the current; (b) last-block reduce fusion --
// the 4th z-block to finish a (v,b) tile sums the 4 partial layers (L2-hot)
// and writes out directly, removing the reduce kernel + its launch gap.
// Tile: 128 v x 64 b x 128 h. Grid (16, 4, 4) = 256 blocks (1/CU).
__global__ __launch_bounds__(256) void pair_kernel(
    const float* __restrict__ EA, const float* __restrict__ EM,
    const float* __restrict__ w2, const float* __restrict__ b2,
    float* __restrict__ partial, float* __restrict__ out,
    int* __restrict__ ctr)
{
    __shared__ float sEA[2][32][68];    // [buf][h][b], 64 cols used
    __shared__ float sEM[2][32][132];   // [buf][h][v], 128 cols used
    __shared__ float4v sC4[32];         // -2*w2 quads for the 128-h chunk
    __shared__ int isLast;
    const int t  = threadIdx.x;
    const int v0 = blockIdx.x * 128;
    const int b0 = blockIdx.y * 64;
    const int h0 = blockIdx.z * 128;
    const int tx = t & 15;   // quad A: v = v0 + tx*4 + j ; quad B: +64
    const int ty = t >> 4;   // b = b0 + ty*4 + i

    if (t < 32) {
        float4v wvq = *(const float4v*)(w2 + h0 + 4 * t);
        sC4[t] = -2.0f * wvq;
    }

    float2v accAL[4], accAH[4], accBL[4], accBH[4];
    #pragma unroll
    for (int i = 0; i < 4; i++) {
        accAL[i] = (float2v){0.f, 0.f};  accAH[i] = (float2v){0.f, 0.f};
        accBL[i] = (float2v){0.f, 0.f};  accBH[i] = (float2v){0.f, 0.f};
    }

    const int rS = t >> 3;          // staging row 0..31
    const int cA = (t & 7) * 8;     // EA cols (64/row, 2 float4)
    const int cM = (t & 7) * 16;    // EM cols (128/row, 4 float4)

    float4v pA0, pA1, pM0, pM1, pM2, pM3;
    // ---- stage 0 (h0 .. h0+31): load + store into buf 0 ----
    {
        const float* pa = EA + (size_t)(h0 + rS) * 256 + b0 + cA;
        pA0 = *(const float4v*)pa;  pA1 = *(const float4v*)(pa + 4);
        const float* pm = EM + (size_t)(h0 + rS) * 2048 + v0 + cM;
        pM0 = *(const float4v*)pm;       pM1 = *(const float4v*)(pm + 4);
        pM2 = *(const float4v*)(pm + 8); pM3 = *(const float4v*)(pm + 12);
    }
    *(float4v*)&sEA[0][rS][cA] = pA0;      *(float4v*)&sEA[0][rS][cA + 4] = pA1;
    *(float4v*)&sEM[0][rS][cM] = pM0;      *(float4v*)&sEM[0][rS][cM + 4] = pM1;
    *(float4v*)&sEM[0][rS][cM + 8] = pM2;  *(float4v*)&sEM[0][rS][cM + 12] = pM3;
    // ---- prefetch stage 1 into registers ----
    {
        const float* pa = EA + (size_t)(h0 + 32 + rS) * 256 + b0 + cA;
        pA0 = *(const float4v*)pa;  pA1 = *(const float4v*)(pa + 4);
        const float* pm = EM + (size_t)(h0 + 32 + rS) * 2048 + v0 + cM;
        pM0 = *(const float4v*)pm;       pM1 = *(const float4v*)(pm + 4);
        pM2 = *(const float4v*)(pm + 8); pM3 = *(const float4v*)(pm + 12);
    }
    __syncthreads();

    #pragma unroll 1
    for (int s = 0; s < 4; s++) {
        const int cur = s & 1, nxt = cur ^ 1;
        if (s < 3) {   // write prefetched stage s+1 into the other buffer
            *(float4v*)&sEA[nxt][rS][cA] = pA0;      *(float4v*)&sEA[nxt][rS][cA + 4] = pA1;
            *(float4v*)&sEM[nxt][rS][cM] = pM0;      *(float4v*)&sEM[nxt][rS][cM + 4] = pM1;
            *(float4v*)&sEM[nxt][rS][cM + 8] = pM2;  *(float4v*)&sEM[nxt][rS][cM + 12] = pM3;
        }
        if (s < 2) {   // issue global loads for stage s+2
            const int hr = h0 + (s + 2) * 32 + rS;
            const float* pa = EA + (size_t)hr * 256 + b0 + cA;
            pA0 = *(const float4v*)pa;  pA1 = *(const float4v*)(pa + 4);
            const float* pm = EM + (size_t)hr * 2048 + v0 + cM;
            pM0 = *(const float4v*)pm;       pM1 = *(const float4v*)(pm + 4);
            pM2 = *(const float4v*)(pm + 8); pM3 = *(const float4v*)(pm + 12);
        }
        #pragma unroll 2
        for (int q = 0; q < 8; q++) {           // 4 h per iteration
            const int hq = 4 * q;
            // ea: 4 b-values per h row (16 addrs x 16B stride, broadcast x4)
            const float4v ea0 = *(const float4v*)&sEA[cur][hq    ][ty * 4];
            const float4v ea1 = *(const float4v*)&sEA[cur][hq + 1][ty * 4];
            const float4v ea2 = *(const float4v*)&sEA[cur][hq + 2][ty * 4];
            const float4v ea3 = *(const float4v*)&sEA[cur][hq + 3][ty * 4];
            const float4v c = sC4[s * 8 + q];
            const float2v c0 = { c.x, c.x };
            const float2v c1 = { c.y, c.y };
            const float2v c2 = { c.z, c.z };
            const float2v c3 = { c.w, c.w };
            // ---- quad A (v = v0 + tx*4) ----
            {
                const float4v em0 = *(const float4v*)&sEM[cur][hq    ][tx * 4];
                const float4v em1 = *(const float4v*)&sEM[cur][hq + 1][tx * 4];
                const float4v em2 = *(const float4v*)&sEM[cur][hq + 2][tx * 4];
                const float4v em3 = *(const float4v*)&sEM[cur][hq + 3][tx * 4];
                const float2v em0L = lo2(em0), em0H = hi2(em0);
                const float2v em1L = lo2(em1), em1H = hi2(em1);
                const float2v em2L = lo2(em2), em2H = hi2(em2);
                const float2v em3L = lo2(em3), em3H = hi2(em3);
                #pragma unroll
                for (int i = 0; i < 4; i++) {
                    const float2v a0 = { ea0[i], ea0[i] };
                    const float2v a1 = { ea1[i], ea1[i] };
                    const float2v a2 = { ea2[i], ea2[i] };
                    const float2v a3 = { ea3[i], ea3[i] };
                    rat4(em0L, em1L, em2L, em3L, a0, a1, a2, a3,
                         c0, c1, c2, c3, accAL[i]);
                    rat4(em0H, em1H, em2H, em3H, a0, a1, a2, a3,
                         c0, c1, c2, c3, accAH[i]);
                }
            }
            // ---- quad B (v = v0 + 64 + tx*4) ----
            {
                const float4v em0 = *(const float4v*)&sEM[cur][hq    ][64 + tx * 4];
                const float4v em1 = *(const float4v*)&sEM[cur][hq + 1][64 + tx * 4];
                const float4v em2 = *(const float4v*)&sEM[cur][hq + 2][64 + tx * 4];
                const float4v em3 = *(const float4v*)&sEM[cur][hq + 3][64 + tx * 4];
                const float2v em0L = lo2(em0), em0H = hi2(em0);
                const float2v em1L = lo2(em1), em1H = hi2(em1);
                const float2v em2L = lo2(em2), em2H = hi2(em2);
                const float2v em3L = lo2(em3), em3H = hi2(em3);
                #pragma unroll
                for (int i = 0; i < 4; i++) {
                    const float2v a0 = { ea0[i], ea0[i] };
                    const float2v a1 = { ea1[i], ea1[i] };
                    const float2v a2 = { ea2[i], ea2[i] };
                    const float2v a3 = { ea3[i], ea3[i] };
                    rat4(em0L, em1L, em2L, em3L, a0, a1, a2, a3,
                         c0, c1, c2, c3, accBL[i]);
                    rat4(em0H, em1H, em2H, em3H, a0, a1, a2, a3,
                         c0, c1, c2, c3, accBH[i]);
                }
            }
        }
        __syncthreads();   // all waves done reading buf[cur] / writing buf[nxt]
    }

    // chunk's sum(w2) from sC4 (sC4 = -2*w2)
    float4v w2q = sC4[0];
    #pragma unroll
    for (int k = 1; k < 32; k++) w2q += sC4[k];
    const float w2s = -0.5f * (w2q.x + w2q.y + w2q.z + w2q.w);

    const size_t pb = (size_t)blockIdx.z * (256 * 2048);
    #pragma unroll
    for (int i = 0; i < 4; i++) {
        const size_t row = pb + (size_t)(b0 + ty * 4 + i) * 2048 + v0 + tx * 4;
        float4v oA = { accAL[i].x + w2s, accAL[i].y + w2s,
                       accAH[i].x + w2s, accAH[i].y + w2s };
        float4v oB = { accBL[i].x + w2s, accBL[i].y + w2s,
                       accBH[i].x + w2s, accBH[i].y + w2s };
        *(float4v*)&partial[row] = oA;
        *(float4v*)&partial[row + 64] = oB;
    }

    // ---- last-block reduce: 4th z-arriver for this (v,b) tile sums layers ----
    __threadfence();                       // release own partial stores
    if (t == 0)
        isLast = (atomicAdd(&ctr[blockIdx.x * 4 + blockIdx.y], 1) == 3);
    __syncthreads();
    if (isLast) {
        __threadfence();                   // acquire other blocks' stores
        const float bb = b2[0];
        #pragma unroll
        for (int k = 0; k < 8; k++) {
            const int f = k * 256 + t;
            const int row = f >> 5;            // 0..63
            const int col = (f & 31) << 2;     // 0..124
            const float* p = partial + (size_t)(b0 + row) * 2048 + v0 + col;
            float4v sum = *(const float4v*)p;
            sum += *(const float4v*)(p + 524288);
            sum += *(const float4v*)(p + 2 * 524288);
            sum += *(const float4v*)(p + 3 * 524288);
            float4v o = sum + bb;
            *(float4v*)&out[(size_t)(b0 + row) * 2048 + v0 + col] = o;
        }
    }
}

extern "C" void kernel_launch(void* const* d_in, const int* in_sizes, int n_in,
                              void* d_out, int out_size, void* d_ws, size_t ws_size,
                              hipStream_t stream)
{
    const float* patient = (const float*)d_in[0]; // 256x1024
    const float* atc4    = (const float*)d_in[1]; // 2048x512
    const float* W1      = (const float*)d_in[2]; // 512x1536
    const float* b1      = (const float*)d_in[3]; // 512
    const float* w2      = (const float*)d_in[4]; // 512
    const float* b2      = (const float*)d_in[5]; // 1
    float* out = (float*)d_out;
    float* ws  = (float*)d_ws;

    // ws layout (floats): EA[512][256], EM[512][2048],
    //                     partial[4][256][2048], ctr[64] => ~13 MB
    float* EA      = ws;
    float* EM      = ws + 131072;
    float* partial = ws + 1179648;
    int*   ctr     = (int*)(ws + 1179648 + 4 * 524288);

    // Both GEMMs in one dispatch (z selects); exp(2x) epilogue; zeroes ctr
    gemm_exp<<<dim3(32, 8, 2), 256, 0, stream>>>(patient, atc4, W1, b1, EA, EM, ctr);
    // score partials + fused last-block reduce (writes out directly)
    pair_kernel<<<dim3(16, 4, 4), 256, 0, stream>>>(EA, EM, w2, b2, partial, out, ctr);
}

// Round 4
// 114.576 us; speedup vs baseline: 1.2629x; 1.2629x over previous
//
#include <hip/hip_runtime.h>
#include <hip/hip_bf16.h>
#include <math.h>

// Problem constants: B=256, V=2048, PD=1024, MD=512, H=512
typedef __attribute__((ext_vector_type(8))) short short8;
typedef __attribute__((ext_vector_type(4))) float float4v;
typedef __attribute__((ext_vector_type(2))) float float2v;

// SSA-safe half extraction (NO unions -- unions block SROA and spill).
__device__ __forceinline__ float2v lo2(float4v v) {
    return __builtin_shufflevector(v, v, 0, 1);
}
__device__ __forceinline__ float2v hi2(float4v v) {
    return __builtin_shufflevector(v, v, 2, 3);
}

__device__ __forceinline__ int2 cvt2bf16x4(float4v v) {
    union { __hip_bfloat162 h2; int i; } u0, u1;
    u0.h2 = __float22bfloat162_rn(make_float2(v.x, v.y));  // v_cvt_pk_bf16_f32
    u1.h2 = __float22bfloat162_rn(make_float2(v.z, v.w));
    return make_int2(u0.i, u1.i);
}

// Fused dual GEMM + exp epilogue (plain [h][x] layout, contiguous stores).
//  bx 0..3:  EA[h][b] = exp(2*(patient@W1p^T + b1))   M=256,  K=1024
//  bx 4..35: EM[h][v] = exp(2*(atc4@W1m^T))           M=2048, K=512
// Round 4: grid compacted (36,8,1) -- no null blocks; heavy EA tiles at low
// bx so the 32-block overflow wave is short EM tiles (smaller tail).
// NOTE (round-3 lesson): do NOT fuse cross-block reductions with
// __threadfence on this chip -- agent-scope fences flush per-XCD L2 and
// cost ~30 us. Separate dispatches keep workspace traffic L2-hot.
__global__ __launch_bounds__(256) void gemm_exp(
    const float* __restrict__ patient, const float* __restrict__ atc4,
    const float* __restrict__ W1, const float* __restrict__ b1,
    float* __restrict__ EA, float* __restrict__ EM)
{
    const float* A; const float* W; const float* bias; float* T;
    int lda, K, M;
    int bx = blockIdx.x;
    if (bx < 4) {
        A = patient; lda = 1024; K = 1024; M = 256; bias = b1; T = EA; W = W1;
    } else {
        bx -= 4;
        A = atc4;    lda = 512;  K = 512;  M = 2048; bias = nullptr; T = EM; W = W1 + 1024;
    }
    const int ldw = 1536;

    __shared__ short As[64][72];
    __shared__ short Bs[64][72];
    const int t = threadIdx.x;
    const int m0 = bx * 64;
    const int n0 = blockIdx.y * 64;
    const int wave = t >> 6;
    const int lane = t & 63;
    const int wm = (wave & 1) * 32;
    const int wn = (wave >> 1) * 32;
    const int lrow = lane & 15;
    const int quad = lane >> 4;

    float4v acc[2][2];
    #pragma unroll
    for (int i = 0; i < 2; i++)
        #pragma unroll
        for (int j = 0; j < 2; j++)
            acc[i][j] = (float4v){0.f, 0.f, 0.f, 0.f};

    const int sr = t >> 2;        // staging row 0..63
    const int sc = (t & 3) * 16;  // staging col 0,16,32,48

    // preload k-tile 0 into registers
    float4v av[4], wv[4];
    {
        const float* ap = A + (size_t)(m0 + sr) * lda + sc;
        const float* wp = W + (size_t)(n0 + sr) * ldw + sc;
        #pragma unroll
        for (int ii = 0; ii < 4; ii++) {
            av[ii] = *(const float4v*)(ap + ii * 4);
            wv[ii] = *(const float4v*)(wp + ii * 4);
        }
    }

    for (int k0 = 0; k0 < K; k0 += 64) {
        #pragma unroll
        for (int ii = 0; ii < 4; ii++) {
            *(int2*)&As[sr][sc + ii * 4] = cvt2bf16x4(av[ii]);
            *(int2*)&Bs[sr][sc + ii * 4] = cvt2bf16x4(wv[ii]);
        }
        __syncthreads();
        if (k0 + 64 < K) {   // prefetch next k-tile; latency hides under MFMA
            const float* ap = A + (size_t)(m0 + sr) * lda + (k0 + 64 + sc);
            const float* wp = W + (size_t)(n0 + sr) * ldw + (k0 + 64 + sc);
            #pragma unroll
            for (int ii = 0; ii < 4; ii++) {
                av[ii] = *(const float4v*)(ap + ii * 4);
                wv[ii] = *(const float4v*)(wp + ii * 4);
            }
        }
        #pragma unroll
        for (int kk = 0; kk < 64; kk += 32) {
            short8 af[2], bfr[2];
            #pragma unroll
            for (int i = 0; i < 2; i++)
                af[i] = *(const short8*)&As[wm + i * 16 + lrow][kk + quad * 8];
            #pragma unroll
            for (int j = 0; j < 2; j++)
                bfr[j] = *(const short8*)&Bs[wn + j * 16 + lrow][kk + quad * 8];
            #pragma unroll
            for (int i = 0; i < 2; i++)
                #pragma unroll
                for (int j = 0; j < 2; j++)
                    acc[i][j] = __builtin_amdgcn_mfma_f32_16x16x32_bf16(
                        af[i], bfr[j], acc[i][j], 0, 0, 0);
        }
        __syncthreads();
    }

    // D layout (verified m89/m91): col(n)=lane&15, row(m)=quad*4+reg
    #pragma unroll
    for (int i = 0; i < 2; i++) {
        #pragma unroll
        for (int j = 0; j < 2; j++) {
            const int n  = n0 + wn + j * 16 + lrow;
            const int mb = m0 + wm + i * 16 + quad * 4;
            const float bn = bias ? bias[n] : 0.0f;
            float4v ev;
            #pragma unroll
            for (int r = 0; r < 4; r++)
                ev[r] = __expf(2.0f * (acc[i][j][r] + bn));
            *(float4v*)&T[(size_t)n * M + mb] = ev;
        }
    }
}

// 4-h rational block: acc += sum_{k=0..3} c_k / d_k, d_k = 1 + em_k*a_k.
//   (n01*e23 + n23*e01)/(e01*e23); all d >= 1 so no cancellation.
__device__ __forceinline__ void rat4(
    float2v em0, float2v em1, float2v em2, float2v em3,
    float2v a0, float2v a1, float2v a2, float2v a3,
    float2v c0, float2v c1, float2v c2, float2v c3,
    float2v& acc)
{
    const float2v one2 = {1.f, 1.f};
    float2v d0 = __builtin_elementwise_fma(em0, a0, one2);
    float2v d1 = __builtin_elementwise_fma(em1, a1, one2);
    float2v d2 = __builtin_elementwise_fma(em2, a2, one2);
    float2v d3 = __builtin_elementwise_fma(em3, a3, one2);
    float2v e01 = d0 * d1;
    float2v e23 = d2 * d3;
    float2v n01 = __builtin_elementwise_fma(d1, c0, d0 * c1);
    float2v n23 = __builtin_elementwise_fma(d3, c2, d2 * c3);
    float2v num = __builtin_elementwise_fma(n01, e23, n23 * e01);
    float2v den = e01 * e23;
    float2v r = { __builtin_amdgcn_rcpf(den.x), __builtin_amdgcn_rcpf(den.y) };
    acc = __builtin_elementwise_fma(num, r, acc);
}

// partial[z][b][v] = sum_{h in 128-chunk z} [ w2[h] + c_h / d_h ],
//   c = -2*w2, d = 1 + Ea[h][b]*Em[h][v]    (w2*tanh(x) = w2 - 2*w2/(1+e^{2x}))
// Round-2 structure (best measured): single-buffered staging with register
// prefetch of the next 32-h stage; no fences, no cross-block traffic.
// Tile: 128 v x 64 b x 128 h. Grid (16, 4, 4) = 256 blocks (1/CU).
__global__ __launch_bounds__(256) void pair_kernel(
    const float* __restrict__ EA, const float* __restrict__ EM,
    const float* __restrict__ w2, float* __restrict__ partial)
{
    __shared__ float sEA[32][68];    // [h][b], 64 cols used
    __shared__ float sEM[32][132];   // [h][v], 128 cols used
    __shared__ float4v sC4[32];      // -2*w2 quads for the 128-h chunk
    const int t  = threadIdx.x;
    const int v0 = blockIdx.x * 128;
    const int b0 = blockIdx.y * 64;
    const int h0 = blockIdx.z * 128;
    const int tx = t & 15;   // quad A: v = v0 + tx*4 + j ; quad B: +64
    const int ty = t >> 4;   // b = b0 + ty*4 + i

    if (t < 32) {
        float4v wvq = *(const float4v*)(w2 + h0 + 4 * t);
        sC4[t] = -2.0f * wvq;
    }

    float2v accAL[4], accAH[4], accBL[4], accBH[4];
    #pragma unroll
    for (int i = 0; i < 4; i++) {
        accAL[i] = (float2v){0.f, 0.f};  accAH[i] = (float2v){0.f, 0.f};
        accBL[i] = (float2v){0.f, 0.f};  accBH[i] = (float2v){0.f, 0.f};
    }

    const int rS = t >> 3;          // staging row 0..31
    const int cA = (t & 7) * 8;     // EA cols (64/row, 2 float4)
    const int cM = (t & 7) * 16;    // EM cols (128/row, 4 float4)

    float4v pA0, pA1, pM0, pM1, pM2, pM3;
    // ---- stage 0 (h0 .. h0+31): load + store ----
    {
        const float* pa = EA + (size_t)(h0 + rS) * 256 + b0 + cA;
        pA0 = *(const float4v*)pa;  pA1 = *(const float4v*)(pa + 4);
        const float* pm = EM + (size_t)(h0 + rS) * 2048 + v0 + cM;
        pM0 = *(const float4v*)pm;       pM1 = *(const float4v*)(pm + 4);
        pM2 = *(const float4v*)(pm + 8); pM3 = *(const float4v*)(pm + 12);
    }
    *(float4v*)&sEA[rS][cA] = pA0;      *(float4v*)&sEA[rS][cA + 4] = pA1;
    *(float4v*)&sEM[rS][cM] = pM0;      *(float4v*)&sEM[rS][cM + 4] = pM1;
    *(float4v*)&sEM[rS][cM + 8] = pM2;  *(float4v*)&sEM[rS][cM + 12] = pM3;
    __syncthreads();

    #pragma unroll 1
    for (int s = 0; s < 4; s++) {
        if (s < 3) {   // prefetch stage s+1; latency hides under compute(s)
            const int hr = h0 + (s + 1) * 32 + rS;
            const float* pa = EA + (size_t)hr * 256 + b0 + cA;
            pA0 = *(const float4v*)pa;  pA1 = *(const float4v*)(pa + 4);
            const float* pm = EM + (size_t)hr * 2048 + v0 + cM;
            pM0 = *(const float4v*)pm;       pM1 = *(const float4v*)(pm + 4);
            pM2 = *(const float4v*)(pm + 8); pM3 = *(const float4v*)(pm + 12);
        }
        #pragma unroll 2
        for (int q = 0; q < 8; q++) {           // 4 h per iteration
            const int hq = 4 * q;
            // ea: 4 b-values per h row (16 addrs x 16B stride, broadcast x4)
            const float4v ea0 = *(const float4v*)&sEA[hq    ][ty * 4];
            const float4v ea1 = *(const float4v*)&sEA[hq + 1][ty * 4];
            const float4v ea2 = *(const float4v*)&sEA[hq + 2][ty * 4];
            const float4v ea3 = *(const float4v*)&sEA[hq + 3][ty * 4];
            const float4v c = sC4[s * 8 + q];
            const float2v c0 = { c.x, c.x };
            const float2v c1 = { c.y, c.y };
            const float2v c2 = { c.z, c.z };
            const float2v c3 = { c.w, c.w };
            // ---- quad A (v = v0 + tx*4) ----
            {
                const float4v em0 = *(const float4v*)&sEM[hq    ][tx * 4];
                const float4v em1 = *(const float4v*)&sEM[hq + 1][tx * 4];
                const float4v em2 = *(const float4v*)&sEM[hq + 2][tx * 4];
                const float4v em3 = *(const float4v*)&sEM[hq + 3][tx * 4];
                const float2v em0L = lo2(em0), em0H = hi2(em0);
                const float2v em1L = lo2(em1), em1H = hi2(em1);
                const float2v em2L = lo2(em2), em2H = hi2(em2);
                const float2v em3L = lo2(em3), em3H = hi2(em3);
                #pragma unroll
                for (int i = 0; i < 4; i++) {
                    const float2v a0 = { ea0[i], ea0[i] };
                    const float2v a1 = { ea1[i], ea1[i] };
                    const float2v a2 = { ea2[i], ea2[i] };
                    const float2v a3 = { ea3[i], ea3[i] };
                    rat4(em0L, em1L, em2L, em3L, a0, a1, a2, a3,
                         c0, c1, c2, c3, accAL[i]);
                    rat4(em0H, em1H, em2H, em3H, a0, a1, a2, a3,
                         c0, c1, c2, c3, accAH[i]);
                }
            }
            // ---- quad B (v = v0 + 64 + tx*4) ----
            {
                const float4v em0 = *(const float4v*)&sEM[hq    ][64 + tx * 4];
                const float4v em1 = *(const float4v*)&sEM[hq + 1][64 + tx * 4];
                const float4v em2 = *(const float4v*)&sEM[hq + 2][64 + tx * 4];
                const float4v em3 = *(const float4v*)&sEM[hq + 3][64 + tx * 4];
                const float2v em0L = lo2(em0), em0H = hi2(em0);
                const float2v em1L = lo2(em1), em1H = hi2(em1);
                const float2v em2L = lo2(em2), em2H = hi2(em2);
                const float2v em3L = lo2(em3), em3H = hi2(em3);
                #pragma unroll
                for (int i = 0; i < 4; i++) {
                    const float2v a0 = { ea0[i], ea0[i] };
                    const float2v a1 = { ea1[i], ea1[i] };
                    const float2v a2 = { ea2[i], ea2[i] };
                    const float2v a3 = { ea3[i], ea3[i] };
                    rat4(em0L, em1L, em2L, em3L, a0, a1, a2, a3,
                         c0, c1, c2, c3, accBL[i]);
                    rat4(em0H, em1H, em2H, em3H, a0, a1, a2, a3,
                         c0, c1, c2, c3, accBH[i]);
                }
            }
        }
        if (s < 3) {
            __syncthreads();   // compute(s) done reading LDS
            *(float4v*)&sEA[rS][cA] = pA0;      *(float4v*)&sEA[rS][cA + 4] = pA1;
            *(float4v*)&sEM[rS][cM] = pM0;      *(float4v*)&sEM[rS][cM + 4] = pM1;
            *(float4v*)&sEM[rS][cM + 8] = pM2;  *(float4v*)&sEM[rS][cM + 12] = pM3;
            __syncthreads();
        }
    }

    // chunk's sum(w2) from sC4 (sC4 = -2*w2)
    float4v w2q = sC4[0];
    #pragma unroll
    for (int k = 1; k < 32; k++) w2q += sC4[k];
    const float w2s = -0.5f * (w2q.x + w2q.y + w2q.z + w2q.w);

    const size_t pb = (size_t)blockIdx.z * (256 * 2048);
    #pragma unroll
    for (int i = 0; i < 4; i++) {
        const size_t row = pb + (size_t)(b0 + ty * 4 + i) * 2048 + v0 + tx * 4;
        float4v oA = { accAL[i].x + w2s, accAL[i].y + w2s,
                       accAH[i].x + w2s, accAH[i].y + w2s };
        float4v oB = { accBL[i].x + w2s, accBL[i].y + w2s,
                       accBH[i].x + w2s, accBH[i].y + w2s };
        *(float4v*)&partial[row] = oA;
        *(float4v*)&partial[row + 64] = oB;
    }
}

__global__ __launch_bounds__(256) void reduce_kernel(
    const float* __restrict__ partial, const float* __restrict__ b2,
    float* __restrict__ out)
{
    const int i = (blockIdx.x * 256 + threadIdx.x) * 4;
    const float bb = b2[0];
    float4v s = *(const float4v*)&partial[i];
    #pragma unroll
    for (int z = 1; z < 4; z++)
        s += *(const float4v*)&partial[(size_t)z * 524288 + i];
    float4v o = s + bb;
    *(float4v*)&out[i] = o;
}

extern "C" void kernel_launch(void* const* d_in, const int* in_sizes, int n_in,
                              void* d_out, int out_size, void* d_ws, size_t ws_size,
                              hipStream_t stream)
{
    const float* patient = (const float*)d_in[0]; // 256x1024
    const float* atc4    = (const float*)d_in[1]; // 2048x512
    const float* W1      = (const float*)d_in[2]; // 512x1536
    const float* b1      = (const float*)d_in[3]; // 512
    const float* w2      = (const float*)d_in[4]; // 512
    const float* b2      = (const float*)d_in[5]; // 1
    float* out = (float*)d_out;
    float* ws  = (float*)d_ws;

    // ws layout (floats): EA[512][256], EM[512][2048], partial[4][256][2048] => 13 MB
    float* EA      = ws;
    float* EM      = ws + 131072;
    float* partial = ws + 1179648;

    // Both GEMMs in one dispatch (compacted grid, EA tiles first); exp(2x) epilogue
    gemm_exp<<<dim3(36, 8, 1), 256, 0, stream>>>(patient, atc4, W1, b1, EA, EM);
    // score partials: 8v x 4b register blocking, 128 h per block (4 stages)
    pair_kernel<<<dim3(16, 4, 4), 256, 0, stream>>>(EA, EM, w2, partial);
    // sum 4 h-chunks + b2
    reduce_kernel<<<512, 256, 0, stream>>>(partial, b2, out);
}

// Round 5
// 112.227 us; speedup vs baseline: 1.2893x; 1.0209x over previous
//
#include <hip/hip_runtime.h>
#include <hip/hip_bf16.h>
#include <math.h>

// Problem constants: B=256, V=2048, PD=1024, MD=512, H=512
typedef __attribute__((ext_vector_type(8))) short short8;
typedef __attribute__((ext_vector_type(4))) float float4v;
typedef __attribute__((ext_vector_type(2))) float float2v;

// SSA-safe half extraction (NO unions -- unions block SROA and spill).
__device__ __forceinline__ float2v lo2(float4v v) {
    return __builtin_shufflevector(v, v, 0, 1);
}
__device__ __forceinline__ float2v hi2(float4v v) {
    return __builtin_shufflevector(v, v, 2, 3);
}

__device__ __forceinline__ int2 cvt2bf16x4(float4v v) {
    union { __hip_bfloat162 h2; int i; } u0, u1;
    u0.h2 = __float22bfloat162_rn(make_float2(v.x, v.y));  // v_cvt_pk_bf16_f32
    u1.h2 = __float22bfloat162_rn(make_float2(v.z, v.w));
    return make_int2(u0.i, u1.i);
}

// Fused dual GEMM + exp epilogue (plain [h][x] layout, contiguous stores).
//  bx 0..3:  EA[h][b] = exp(2*(patient@W1p^T + b1))   M=256,  K=1024
//  bx 4..35: EM[h][v] = exp(2*(atc4@W1m^T))           M=2048, K=512
// NOTE (round-3 lesson): do NOT fuse cross-block reductions with
// __threadfence on this chip -- agent-scope fences flush per-XCD L2 and
// cost ~30 us. Separate dispatches keep workspace traffic L2-hot.
__global__ __launch_bounds__(256) void gemm_exp(
    const float* __restrict__ patient, const float* __restrict__ atc4,
    const float* __restrict__ W1, const float* __restrict__ b1,
    float* __restrict__ EA, float* __restrict__ EM)
{
    const float* A; const float* W; const float* bias; float* T;
    int lda, K, M;
    int bx = blockIdx.x;
    if (bx < 4) {
        A = patient; lda = 1024; K = 1024; M = 256; bias = b1; T = EA; W = W1;
    } else {
        bx -= 4;
        A = atc4;    lda = 512;  K = 512;  M = 2048; bias = nullptr; T = EM; W = W1 + 1024;
    }
    const int ldw = 1536;

    __shared__ short As[64][72];
    __shared__ short Bs[64][72];
    const int t = threadIdx.x;
    const int m0 = bx * 64;
    const int n0 = blockIdx.y * 64;
    const int wave = t >> 6;
    const int lane = t & 63;
    const int wm = (wave & 1) * 32;
    const int wn = (wave >> 1) * 32;
    const int lrow = lane & 15;
    const int quad = lane >> 4;

    float4v acc[2][2];
    #pragma unroll
    for (int i = 0; i < 2; i++)
        #pragma unroll
        for (int j = 0; j < 2; j++)
            acc[i][j] = (float4v){0.f, 0.f, 0.f, 0.f};

    const int sr = t >> 2;        // staging row 0..63
    const int sc = (t & 3) * 16;  // staging col 0,16,32,48

    // preload k-tile 0 into registers
    float4v av[4], wv[4];
    {
        const float* ap = A + (size_t)(m0 + sr) * lda + sc;
        const float* wp = W + (size_t)(n0 + sr) * ldw + sc;
        #pragma unroll
        for (int ii = 0; ii < 4; ii++) {
            av[ii] = *(const float4v*)(ap + ii * 4);
            wv[ii] = *(const float4v*)(wp + ii * 4);
        }
    }

    for (int k0 = 0; k0 < K; k0 += 64) {
        #pragma unroll
        for (int ii = 0; ii < 4; ii++) {
            *(int2*)&As[sr][sc + ii * 4] = cvt2bf16x4(av[ii]);
            *(int2*)&Bs[sr][sc + ii * 4] = cvt2bf16x4(wv[ii]);
        }
        __syncthreads();
        if (k0 + 64 < K) {   // prefetch next k-tile; latency hides under MFMA
            const float* ap = A + (size_t)(m0 + sr) * lda + (k0 + 64 + sc);
            const float* wp = W + (size_t)(n0 + sr) * ldw + (k0 + 64 + sc);
            #pragma unroll
            for (int ii = 0; ii < 4; ii++) {
                av[ii] = *(const float4v*)(ap + ii * 4);
                wv[ii] = *(const float4v*)(wp + ii * 4);
            }
        }
        #pragma unroll
        for (int kk = 0; kk < 64; kk += 32) {
            short8 af[2], bfr[2];
            #pragma unroll
            for (int i = 0; i < 2; i++)
                af[i] = *(const short8*)&As[wm + i * 16 + lrow][kk + quad * 8];
            #pragma unroll
            for (int j = 0; j < 2; j++)
                bfr[j] = *(const short8*)&Bs[wn + j * 16 + lrow][kk + quad * 8];
            #pragma unroll
            for (int i = 0; i < 2; i++)
                #pragma unroll
                for (int j = 0; j < 2; j++)
                    acc[i][j] = __builtin_amdgcn_mfma_f32_16x16x32_bf16(
                        af[i], bfr[j], acc[i][j], 0, 0, 0);
        }
        __syncthreads();
    }

    // D layout (verified m89/m91): col(n)=lane&15, row(m)=quad*4+reg
    #pragma unroll
    for (int i = 0; i < 2; i++) {
        #pragma unroll
        for (int j = 0; j < 2; j++) {
            const int n  = n0 + wn + j * 16 + lrow;
            const int mb = m0 + wm + i * 16 + quad * 4;
            const float bn = bias ? bias[n] : 0.0f;
            float4v ev;
            #pragma unroll
            for (int r = 0; r < 4; r++)
                ev[r] = __expf(2.0f * (acc[i][j][r] + bn));
            *(float4v*)&T[(size_t)n * M + mb] = ev;
        }
    }
}

// 4-h rational block: acc += sum_{k=0..3} c_k / d_k, d_k = 1 + em_k*a_k.
//   (n01*e23 + n23*e01)/(e01*e23); all d >= 1 so no cancellation.
__device__ __forceinline__ void rat4(
    float2v em0, float2v em1, float2v em2, float2v em3,
    float2v a0, float2v a1, float2v a2, float2v a3,
    float2v c0, float2v c1, float2v c2, float2v c3,
    float2v& acc)
{
    const float2v one2 = {1.f, 1.f};
    float2v d0 = __builtin_elementwise_fma(em0, a0, one2);
    float2v d1 = __builtin_elementwise_fma(em1, a1, one2);
    float2v d2 = __builtin_elementwise_fma(em2, a2, one2);
    float2v d3 = __builtin_elementwise_fma(em3, a3, one2);
    float2v e01 = d0 * d1;
    float2v e23 = d2 * d3;
    float2v n01 = __builtin_elementwise_fma(d1, c0, d0 * c1);
    float2v n23 = __builtin_elementwise_fma(d3, c2, d2 * c3);
    float2v num = __builtin_elementwise_fma(n01, e23, n23 * e01);
    float2v den = e01 * e23;
    float2v r = { __builtin_amdgcn_rcpf(den.x), __builtin_amdgcn_rcpf(den.y) };
    acc = __builtin_elementwise_fma(num, r, acc);
}

// partial[z][b][v] = sum_{h in 32-chunk z} [ w2[h] + c_h / d_h ],
//   c = -2*w2, d = 1 + Ea[h][b]*Em[h][v]    (w2*tanh(x) = w2 - 2*w2/(1+e^{2x}))
// Round 5: single-stage blocks. Round-4 counters showed pair at 41.5 us,
// Occupancy 9.4% (1 wave/SIMD), VALUBusy 35% -- latency-bound from the
// 1-block/CU grid. Each block now stages its 32-h chunk once (one barrier,
// no restage loop) and the grid is (16,4,16) = 1024 blocks = 4 blocks/CU
// = 4 waves/SIMD. Register blocking stays 8v x 4b (1.5 B/term LDS).
__global__ __launch_bounds__(256) void pair_kernel(
    const float* __restrict__ EA, const float* __restrict__ EM,
    const float* __restrict__ w2, float* __restrict__ partial)
{
    __shared__ float sEA[32][68];    // [h][b], 64 cols used
    __shared__ float sEM[32][132];   // [h][v], 128 cols used
    __shared__ float4v sC4[8];       // -2*w2 quads for the 32-h chunk
    const int t  = threadIdx.x;
    const int v0 = blockIdx.x * 128;
    const int b0 = blockIdx.y * 64;
    const int h0 = blockIdx.z * 32;
    const int tx = t & 15;   // quad A: v = v0 + tx*4 + j ; quad B: +64
    const int ty = t >> 4;   // b = b0 + ty*4 + i

    if (t < 8) {
        float4v wvq = *(const float4v*)(w2 + h0 + 4 * t);
        sC4[t] = -2.0f * wvq;
    }

    float2v accAL[4], accAH[4], accBL[4], accBH[4];
    #pragma unroll
    for (int i = 0; i < 4; i++) {
        accAL[i] = (float2v){0.f, 0.f};  accAH[i] = (float2v){0.f, 0.f};
        accBL[i] = (float2v){0.f, 0.f};  accBH[i] = (float2v){0.f, 0.f};
    }

    const int rS = t >> 3;          // staging row 0..31
    const int cA = (t & 7) * 8;     // EA cols (64/row, 2 float4)
    const int cM = (t & 7) * 16;    // EM cols (128/row, 4 float4)

    // ---- stage the block's 32-h chunk (once) ----
    {
        const float* pa = EA + (size_t)(h0 + rS) * 256 + b0 + cA;
        float4v pA0 = *(const float4v*)pa;
        float4v pA1 = *(const float4v*)(pa + 4);
        const float* pm = EM + (size_t)(h0 + rS) * 2048 + v0 + cM;
        float4v pM0 = *(const float4v*)pm;
        float4v pM1 = *(const float4v*)(pm + 4);
        float4v pM2 = *(const float4v*)(pm + 8);
        float4v pM3 = *(const float4v*)(pm + 12);
        *(float4v*)&sEA[rS][cA] = pA0;      *(float4v*)&sEA[rS][cA + 4] = pA1;
        *(float4v*)&sEM[rS][cM] = pM0;      *(float4v*)&sEM[rS][cM + 4] = pM1;
        *(float4v*)&sEM[rS][cM + 8] = pM2;  *(float4v*)&sEM[rS][cM + 12] = pM3;
    }
    __syncthreads();

    #pragma unroll 2
    for (int q = 0; q < 8; q++) {           // 4 h per iteration
        const int hq = 4 * q;
        // ea: 4 b-values per h row (broadcast within 16-lane groups)
        const float4v ea0 = *(const float4v*)&sEA[hq    ][ty * 4];
        const float4v ea1 = *(const float4v*)&sEA[hq + 1][ty * 4];
        const float4v ea2 = *(const float4v*)&sEA[hq + 2][ty * 4];
        const float4v ea3 = *(const float4v*)&sEA[hq + 3][ty * 4];
        const float4v c = sC4[q];
        const float2v c0 = { c.x, c.x };
        const float2v c1 = { c.y, c.y };
        const float2v c2 = { c.z, c.z };
        const float2v c3 = { c.w, c.w };
        // ---- quad A (v = v0 + tx*4) ----
        {
            const float4v em0 = *(const float4v*)&sEM[hq    ][tx * 4];
            const float4v em1 = *(const float4v*)&sEM[hq + 1][tx * 4];
            const float4v em2 = *(const float4v*)&sEM[hq + 2][tx * 4];
            const float4v em3 = *(const float4v*)&sEM[hq + 3][tx * 4];
            const float2v em0L = lo2(em0), em0H = hi2(em0);
            const float2v em1L = lo2(em1), em1H = hi2(em1);
            const float2v em2L = lo2(em2), em2H = hi2(em2);
            const float2v em3L = lo2(em3), em3H = hi2(em3);
            #pragma unroll
            for (int i = 0; i < 4; i++) {
                const float2v a0 = { ea0[i], ea0[i] };
                const float2v a1 = { ea1[i], ea1[i] };
                const float2v a2 = { ea2[i], ea2[i] };
                const float2v a3 = { ea3[i], ea3[i] };
                rat4(em0L, em1L, em2L, em3L, a0, a1, a2, a3,
                     c0, c1, c2, c3, accAL[i]);
                rat4(em0H, em1H, em2H, em3H, a0, a1, a2, a3,
                     c0, c1, c2, c3, accAH[i]);
            }
        }
        // ---- quad B (v = v0 + 64 + tx*4) ----
        {
            const float4v em0 = *(const float4v*)&sEM[hq    ][64 + tx * 4];
            const float4v em1 = *(const float4v*)&sEM[hq + 1][64 + tx * 4];
            const float4v em2 = *(const float4v*)&sEM[hq + 2][64 + tx * 4];
            const float4v em3 = *(const float4v*)&sEM[hq + 3][64 + tx * 4];
            const float2v em0L = lo2(em0), em0H = hi2(em0);
            const float2v em1L = lo2(em1), em1H = hi2(em1);
            const float2v em2L = lo2(em2), em2H = hi2(em2);
            const float2v em3L = lo2(em3), em3H = hi2(em3);
            #pragma unroll
            for (int i = 0; i < 4; i++) {
                const float2v a0 = { ea0[i], ea0[i] };
                const float2v a1 = { ea1[i], ea1[i] };
                const float2v a2 = { ea2[i], ea2[i] };
                const float2v a3 = { ea3[i], ea3[i] };
                rat4(em0L, em1L, em2L, em3L, a0, a1, a2, a3,
                     c0, c1, c2, c3, accBL[i]);
                rat4(em0H, em1H, em2H, em3H, a0, a1, a2, a3,
                     c0, c1, c2, c3, accBH[i]);
            }
        }
    }

    // chunk's sum(w2) from sC4 (sC4 = -2*w2)
    float4v w2q = sC4[0];
    #pragma unroll
    for (int k = 1; k < 8; k++) w2q += sC4[k];
    const float w2s = -0.5f * (w2q.x + w2q.y + w2q.z + w2q.w);

    const size_t pb = (size_t)blockIdx.z * (256 * 2048);
    #pragma unroll
    for (int i = 0; i < 4; i++) {
        const size_t row = pb + (size_t)(b0 + ty * 4 + i) * 2048 + v0 + tx * 4;
        float4v oA = { accAL[i].x + w2s, accAL[i].y + w2s,
                       accAH[i].x + w2s, accAH[i].y + w2s };
        float4v oB = { accBL[i].x + w2s, accBL[i].y + w2s,
                       accBH[i].x + w2s, accBH[i].y + w2s };
        *(float4v*)&partial[row] = oA;
        *(float4v*)&partial[row + 64] = oB;
    }
}

__global__ __launch_bounds__(256) void reduce_kernel(
    const float* __restrict__ partial, const float* __restrict__ b2,
    float* __restrict__ out)
{
    const int i = (blockIdx.x * 256 + threadIdx.x) * 4;
    const float bb = b2[0];
    float4v s = *(const float4v*)&partial[i];
    #pragma unroll
    for (int z = 1; z < 16; z++)
        s += *(const float4v*)&partial[(size_t)z * 524288 + i];
    float4v o = s + bb;
    *(float4v*)&out[i] = o;
}

extern "C" void kernel_launch(void* const* d_in, const int* in_sizes, int n_in,
                              void* d_out, int out_size, void* d_ws, size_t ws_size,
                              hipStream_t stream)
{
    const float* patient = (const float*)d_in[0]; // 256x1024
    const float* atc4    = (const float*)d_in[1]; // 2048x512
    const float* W1      = (const float*)d_in[2]; // 512x1536
    const float* b1      = (const float*)d_in[3]; // 512
    const float* w2      = (const float*)d_in[4]; // 512
    const float* b2      = (const float*)d_in[5]; // 1
    float* out = (float*)d_out;
    float* ws  = (float*)d_ws;

    // ws layout (floats): EA[512][256], EM[512][2048],
    //                     partial[16][256][2048] => ~38 MB
    float* EA      = ws;
    float* EM      = ws + 131072;
    float* partial = ws + 1179648;

    // Both GEMMs in one dispatch (compacted grid, EA tiles first); exp(2x) epilogue
    gemm_exp<<<dim3(36, 8, 1), 256, 0, stream>>>(patient, atc4, W1, b1, EA, EM);
    // score partials: single-stage 32-h blocks, 4 blocks/CU
    pair_kernel<<<dim3(16, 4, 16), 256, 0, stream>>>(EA, EM, w2, partial);
    // sum 16 h-chunks + b2
    reduce_kernel<<<512, 256, 0, stream>>>(partial, b2, out);
}